// Round 7
// baseline (3338.705 us; speedup 1.0000x reference)
//
#include <hip/hip_runtime.h>
#include <stdint.h>

#define L 18
#define DIM (1 << L)
#define MKRY 64
#define NBLOCK 256
#define TPB 1024

// ---------------- threefry2x32 (JAX) ----------------
__device__ __forceinline__ uint32_t rotl32(uint32_t v, int r){ return (v<<r)|(v>>(32-r)); }

__device__ __forceinline__ void threefry2x32(uint32_t k0, uint32_t k1, uint32_t x0, uint32_t x1,
                                             uint32_t& o0, uint32_t& o1) {
  uint32_t k2 = k0 ^ k1 ^ 0x1BD11BDAu;
  x0 += k0; x1 += k1;
  x0+=x1; x1=rotl32(x1,13); x1^=x0;
  x0+=x1; x1=rotl32(x1,15); x1^=x0;
  x0+=x1; x1=rotl32(x1,26); x1^=x0;
  x0+=x1; x1=rotl32(x1,6);  x1^=x0;
  x0+=k1; x1+=k2+1u;
  x0+=x1; x1=rotl32(x1,17); x1^=x0;
  x0+=x1; x1=rotl32(x1,29); x1^=x0;
  x0+=x1; x1=rotl32(x1,16); x1^=x0;
  x0+=x1; x1=rotl32(x1,24); x1^=x0;
  x0+=k2; x1+=k0+2u;
  x0+=x1; x1=rotl32(x1,13); x1^=x0;
  x0+=x1; x1=rotl32(x1,15); x1^=x0;
  x0+=x1; x1=rotl32(x1,26); x1^=x0;
  x0+=x1; x1=rotl32(x1,6);  x1^=x0;
  x0+=k0; x1+=k1+3u;
  x0+=x1; x1=rotl32(x1,17); x1^=x0;
  x0+=x1; x1=rotl32(x1,29); x1^=x0;
  x0+=x1; x1=rotl32(x1,16); x1^=x0;
  x0+=x1; x1=rotl32(x1,24); x1^=x0;
  x0+=k1; x1+=k2+4u;
  x0+=x1; x1=rotl32(x1,13); x1^=x0;
  x0+=x1; x1=rotl32(x1,15); x1^=x0;
  x0+=x1; x1=rotl32(x1,26); x1^=x0;
  x0+=x1; x1=rotl32(x1,6);  x1^=x0;
  x0+=k2; x1+=k0+5u;
  o0=x0; o1=x1;
}

__device__ float jax_erfinv(float x){
  #pragma clang fp contract(off)
  float w = -log1pf(-x*x);
  float p;
  if (w < 5.0f) {
    w = w - 2.5f;
    p = 2.81022636e-08f;
    p = 3.43273939e-07f + p*w;
    p = -3.5233877e-06f + p*w;
    p = -4.39150654e-06f + p*w;
    p = 0.00021858087f + p*w;
    p = -0.00125372503f + p*w;
    p = -0.00417768164f + p*w;
    p = 0.246640727f + p*w;
    p = 1.50140941f + p*w;
  } else {
    w = sqrtf(w) - 3.0f;
    p = -0.000200214257f;
    p = 0.000100950558f + p*w;
    p = 0.00134934322f + p*w;
    p = -0.00367342844f + p*w;
    p = 0.00573950773f + p*w;
    p = -0.0076224613f + p*w;
    p = 0.00943887047f + p*w;
    p = 1.00167406f + p*w;
    p = 2.83297682f + p*w;
  }
  return p*x;
}

__device__ __forceinline__ float rng_val(unsigned i){
  #pragma clang fp contract(off)
  uint32_t o0,o1; threefry2x32(0u,42u,0u,i,o0,o1);
  uint32_t bits = o0 ^ o1;
  float f = __uint_as_float((bits >> 9) | 0x3f800000u) - 1.0f;
  const float lo = -0.99999994f;
  float u = f*2.0f;
  u = u + lo;
  u = fmaxf(lo, u);
  return 1.41421354f * jax_erfinv(u);
}

// Deterministic block reduce of two doubles; result broadcast to all threads.
__device__ __forceinline__ double2 blockReduce2(double a, double b){
  __shared__ double sa[16], sb[16], res[2];
  int lane = threadIdx.x & 63, wid = threadIdx.x >> 6;
  #pragma unroll
  for (int off=32; off; off>>=1){ a += __shfl_down(a,off,64); b += __shfl_down(b,off,64); }
  if (lane==0){ sa[wid]=a; sb[wid]=b; }
  __syncthreads();
  if (wid==0){
    double xa = (lane<16)? sa[lane] : 0.0;
    double xb = (lane<16)? sb[lane] : 0.0;
    #pragma unroll
    for (int off=8; off; off>>=1){ xa += __shfl_down(xa,off,64); xb += __shfl_down(xb,off,64); }
    if (lane==0){ res[0]=xa; res[1]=xb; }
  }
  __syncthreads();
  double2 r; r.x=res[0]; r.y=res[1];
  return r;
}

// ---------------- custom grid barrier (requires co-resident launch) ----------------
__device__ __forceinline__ void gbar(unsigned* bar, unsigned epoch){
  __syncthreads();
  if (threadIdx.x==0){
    unsigned prev = __hip_atomic_fetch_add(&bar[0], 1u, __ATOMIC_ACQ_REL, __HIP_MEMORY_SCOPE_AGENT);
    if (prev == NBLOCK-1u){
      __hip_atomic_store(&bar[0], 0u, __ATOMIC_RELAXED, __HIP_MEMORY_SCOPE_AGENT);
      __hip_atomic_fetch_add(&bar[1], 1u, __ATOMIC_RELEASE, __HIP_MEMORY_SCOPE_AGENT);
    } else {
      unsigned g; unsigned guard=0;
      do {
        g = __hip_atomic_load(&bar[1], __ATOMIC_RELAXED, __HIP_MEMORY_SCOPE_AGENT);
        if (g >= epoch) break;
        __builtin_amdgcn_s_sleep(1);
      } while (++guard < (1u<<20));
      (void)__hip_atomic_load(&bar[1], __ATOMIC_ACQUIRE, __HIP_MEMORY_SCOPE_AGENT);
    }
  }
  __syncthreads();
}

// ---------------- matrix-free H, neighbor access via functor ----------------
struct GetDir {
  const float* lds; const float* arr;
  __device__ __forceinline__ float operator()(unsigned nb, bool intra) const {
    return intra ? lds[nb & 1023u] : arr[nb];
  }
};
struct GetRng {  // recompute v0[nb] = rng(nb)/nrm
  const float* lds; float nrm;
  __device__ __forceinline__ float operator()(unsigned nb, bool intra) const {
    if (intra) return lds[nb & 1023u];
    return __fdiv_rn(rng_val(nb), nrm);
  }
};

template<class G>
__device__ __forceinline__ float matvec_g(int s, float vs, const float* hxz, const G& g){
  #pragma clang fp contract(off)
  float acc = 0.0f;
  // bonds i=0..16, site i = bit (17-i), site i+1 = bit (16-i)
  #pragma unroll
  for (int i=0;i<L-1;++i){
    const int q = L-2-i;
    const unsigned msk = 3u<<q;
    const bool intra = (msk < 1024u);
    unsigned b2 = ((unsigned)s >> q) & 3u;
    if (b2==0u || b2==3u) { acc = acc + 0.25f*vs; }
    else if (b2==1u) { float t = -0.25f*vs; t = t + 0.5f*g((unsigned)s^msk, intra); acc = acc + t; }
    else             { float t = 0.5f*g((unsigned)s^msk, intra); t = t + (-0.25f)*vs; acc = acc + t; }
  }
  // fields i=0..17, site i = bit (17-i)
  #pragma unroll
  for (int i=0;i<L;++i){
    const int p = L-1-i;
    const unsigned msk = 1u<<p;
    const bool intra = (msk < 1024u);
    float hx = hxz[i], hz = hxz[18+i];
    float t;
    if ((unsigned)s & msk) { t = hx*g((unsigned)s^msk, intra); t = t + (-hz)*vs; }
    else                   { t = hz*vs; t = t + hx*g((unsigned)s^msk, intra); }
    acc = acc + t;
  }
  return acc;
}

// scal layout (floats): [0..63] alphas | [64..127] betas | [129] nrm |
// [130..147] hx | [148..165] hz | [192..447] U (64x4)

__global__ void k_init(unsigned* bar){ bar[0]=0u; bar[1]=0u; }

__global__ void __launch_bounds__(TPB) k_pass1(const float* __restrict__ B0,
        const float* __restrict__ Bext, const float* __restrict__ phi,
        float* __restrict__ vbase, int vmod,
        double* __restrict__ part, float* scal, unsigned* bar){
  __shared__ float lds_v[TPB];
  __shared__ float lds_hxz[36];
  const int tid = threadIdx.x, bid = blockIdx.x;
  const int s = bid*TPB + tid;

  if (bid==0 && tid < L){
    #pragma clang fp contract(off)
    float b0 = B0[0], be = Bext[0];
    double ph = (double)phi[tid];
    float Bx = b0*(float)sin(ph);
    float Bz = b0*(float)cos(ph);
    Bz = Bz + be;
    scal[130+tid] = 0.5f*Bx;
    scal[148+tid] = 0.5f*Bz;
  }

  float n = rng_val((unsigned)s);
  {
    double2 pr = blockReduce2((double)n*(double)n, 0.0);
    double* pb = part + 512;
    if (tid==0){ pb[2*bid]=pr.x; pb[2*bid+1]=pr.y; }
  }
  gbar(bar, 1);

  if (tid < 36) lds_hxz[tid] = scal[130+tid];

  float v_reg;
  float nrm;
  {
    double pa=0.0, pbv=0.0;
    const double* pb = part + 512;
    if (tid<NBLOCK){ pa=pb[2*tid]; pbv=pb[2*tid+1]; }
    double2 t = blockReduce2(pa, pbv);
    nrm = (float)sqrt(t.x);
    v_reg = __fdiv_rn(n, nrm);
    vbase[s] = v_reg;          // slot 0 = v_0
    if (s==0) scal[129] = nrm;
    lds_v[tid] = v_reg;
  }
  float vp_reg = 0.0f, b_p = 0.0f;
  gbar(bar, 2);

  const float* cur = vbase;
  for (int m=0; m<MKRY; ++m){
    float w;
    {
      GetDir g{lds_v, cur};
      w = matvec_g(s, v_reg, lds_hxz, g);
    }
    double2 p2 = blockReduce2((double)v_reg*(double)w, (double)w*(double)w);
    double* pb = part + (size_t)(m&1)*512;
    if (tid==0){ pb[2*bid]=p2.x; pb[2*bid+1]=p2.y; }
    gbar(bar, 3+2*(unsigned)m);

    double xa=0.0, xb=0.0;
    if (tid<NBLOCK){ xa=pb[2*tid]; xb=pb[2*tid+1]; }
    double2 tt = blockReduce2(xa, xb);
    float alpha = (float)tt.x;
    double b2d = tt.y - tt.x*tt.x - (double)b_p*(double)b_p;
    float beta = (float)sqrt(fmax(b2d, 0.0));

    float x;
    {
      #pragma clang fp contract(off)
      x = w - alpha*v_reg;
      x = x - b_p*vp_reg;
    }
    float vn = __fdiv_rn(x, fmaxf(beta, 1e-12f));
    if (s==0){ scal[m]=alpha; scal[64+m]=beta; }

    float* nxt = vbase + (size_t)((m+1)%vmod)*DIM;
    nxt[s] = vn;
    lds_v[tid] = vn;
    b_p=beta; vp_reg=v_reg; v_reg=vn;
    gbar(bar, 4+2*(unsigned)m);   // v_{m+1} visible for next matvec
    cur = nxt;
  }
}

// big-ws: V fully stored, pass2 is a trivial accumulate
__global__ void __launch_bounds__(256) k_pass2s(const float* __restrict__ vbase,
        const float* __restrict__ scal, float* __restrict__ out){
  __shared__ float U[256];
  int tid = threadIdx.x;
  int s = blockIdx.x*256 + tid;
  U[tid] = scal[192+tid];
  __syncthreads();
  {
    #pragma clang fp contract(off)
    float o0=0.0f,o1=0.0f,o2=0.0f,o3=0.0f;
    for (int m=0;m<MKRY;++m){
      float vm = vbase[(size_t)m*DIM + s];
      o0 = o0 + vm*U[4*m+0];
      o1 = o1 + vm*U[4*m+1];
      o2 = o2 + vm*U[4*m+2];
      o3 = o3 + vm*U[4*m+3];
    }
    *(float4*)(out + 4 + 4*(size_t)s) = make_float4(o0,o1,o2,o3);
  }
}

// small-ws: cooperative pass2, direct gather (alphas/betas known)
__global__ void __launch_bounds__(TPB) k_pass2c(float* __restrict__ vbase, int vmod,
        const float* __restrict__ scal, float* __restrict__ out,
        unsigned* bar, int baseEpoch){
  __shared__ float lds_v[TPB];
  __shared__ float lds_hxz[36];
  __shared__ float lds_ab[384];
  const int tid = threadIdx.x, bid = blockIdx.x;
  const int s = bid*TPB + tid;
  if (tid < 36) lds_hxz[tid] = scal[130+tid];
  if (tid < 128) lds_ab[tid] = scal[tid];
  if (tid >= 128 && tid < 384) lds_ab[tid] = scal[192 + (tid-128)];
  float nrm = scal[129];
  float n = rng_val((unsigned)s);
  float v_reg = __fdiv_rn(n, nrm);
  float vp_reg = 0.0f;
  lds_v[tid] = v_reg;
  float o0=0.0f,o1=0.0f,o2=0.0f,o3=0.0f;
  for (int m=0;m<MKRY;++m){
    if (m>0) (vbase + (size_t)(m%vmod)*DIM)[s] = v_reg;
    gbar(bar, (unsigned)(baseEpoch+1+m));
    float w;
    if (m==0){
      GetRng g{lds_v, nrm};
      w = matvec_g(s, v_reg, lds_hxz, g);
    } else {
      GetDir g{lds_v, vbase + (size_t)(m%vmod)*DIM};
      w = matvec_g(s, v_reg, lds_hxz, g);
    }
    float alpha = lds_ab[m];
    float bp = (m==0)? 0.0f : lds_ab[64+m-1];
    float beta = fmaxf(lds_ab[64+m], 1e-12f);
    float x;
    {
      #pragma clang fp contract(off)
      x = w - alpha*v_reg;
      x = x - bp*vp_reg;
    }
    float vn = __fdiv_rn(x, beta);
    {
      #pragma clang fp contract(off)
      o0 = o0 + v_reg*lds_ab[128+4*m+0];
      o1 = o1 + v_reg*lds_ab[128+4*m+1];
      o2 = o2 + v_reg*lds_ab[128+4*m+2];
      o3 = o3 + v_reg*lds_ab[128+4*m+3];
    }
    vp_reg = v_reg; v_reg = vn;
    __syncthreads();
    lds_v[tid] = vn;
  }
  *(float4*)(out + 4 + 4*(size_t)s) = make_float4(o0,o1,o2,o3);
}

// tql2 (EISPACK) f64 v3: dd/ee fully register-resident (lane t holds index t),
// __shfl broadcasts on the chain (reads at i-1 are pre-sweep: updates only touch
// indices >= i+1), lane-predicated register updates (no LDS on the serial path),
// fast rsqrt (f32 seed + 2 f64 NR), Z-row application fused for ILP overlap.
// Rotation FP order identical to R5/R6 (up to rsqrt rounding at ~1e-16).
__global__ void k_eigh(float* __restrict__ scal, float* __restrict__ out){
  __shared__ double Z[64][65];
  int t = threadIdx.x;
  double ddv = (double)scal[t];
  double eev = (t<63)? (double)scal[64+t] : 0.0;
  for (int j=0;j<64;++j) Z[t][j] = (t==j)?1.0:0.0;
  __syncthreads();

  for (int l=0;l<64;++l){
    for (int iter=0; iter<80; ++iter){
      // ---- parallel deflation scan (register-based)
      double dt1 = __shfl_down(ddv, 1, 64);
      bool cond = (t>=l) && (t<63) &&
                  (fabs(eev) <= 2.220446049250313e-16 * (fabs(ddv)+fabs(dt1)));
      unsigned long long bm = __ballot(cond) | (1ull<<63);
      int m = __builtin_ctzll(bm);
      if (m==l) break;
      // ---- shift
      double dd_l  = __shfl(ddv, l, 64);
      double dd_l1 = __shfl(ddv, l+1, 64);
      double dd_m  = __shfl(ddv, m, 64);
      double ee_l  = __shfl(eev, l, 64);
      double g = (dd_l1-dd_l)/(2.0*ee_l);
      double r = sqrt(fma(g,g,1.0));
      g = dd_m-dd_l + ee_l/(g + copysign(r,g));
      double s=1.0, c=1.0, p=0.0;
      int stop = l;
      // ---- fused chain + Z apply
      double ee_i  = __shfl(eev, m-1, 64);
      double dd_i  = __shfl(ddv, m-1, 64);
      double dd_i1 = dd_m;
      double zhi = Z[t][m];
      for (int i=m-1; i>=l; --i){
        double ee_n=0.0, dd_n=0.0;
        if (i>l){ ee_n = __shfl(eev, i-1, 64); dd_n = __shfl(ddv, i-1, 64); }
        double f = s*ee_i, b = c*ee_i;
        double h = fma(f,f,g*g);
        if (h==0.0){
          if (t==i+1) ddv = dd_i1 - p;
          if (t==m) eev = 0.0;
          stop = i+1;
          break;
        }
        double inv;
        if (h < 1e-35){
          inv = 1.0/sqrt(h);
        } else {
          double x0 = (double)__frsqrt_rn((float)h);
          x0 = x0*(1.5 - 0.5*h*x0*x0);
          inv = x0*(1.5 - 0.5*h*x0*x0);
        }
        s = f*inv; c = g*inv;
        double rr = h*inv;            // = sqrt(h)
        g = dd_i1 - p;
        double r2 = (dd_i - g)*s + 2.0*c*b;
        p = s*r2;
        double ddw = g + p;
        g = c*r2 - b;
        if (t==i+1){ ddv = ddw; eev = rr; }
        // Z rotation i on own row (carry)
        double zlo = Z[t][i];
        Z[t][i+1] = s*zlo + c*zhi;
        zhi = c*zlo - s*zhi;
        dd_i1 = dd_i; ee_i = ee_n; dd_i = dd_n;
        if (i==l){
          if (t==l){ ddv = ddv - p; eev = g; }
          if (t==m){ eev = 0.0; }
        }
      }
      Z[t][stop] = zhi;
      __syncthreads();
    }
  }
  // ---- shfl-based ascending selection sort (first-min-index)
  double dv = ddv;
  for (int k=0;k<63;++k){
    double mv = (t>=k)? dv : 1.0e300;
    int mi = t;
    #pragma unroll
    for (int off=32; off; off>>=1){
      double ov = __shfl_down(mv, off, 64);
      int    oi = __shfl_down(mi, off, 64);
      if (ov < mv || (ov==mv && oi<mi)){ mv=ov; mi=oi; }
    }
    int jm = __shfl(mi, 0, 64);
    if (jm!=k){
      int src = (t==k)? jm : ((t==jm)? k : t);
      dv = __shfl(dv, src, 64);
      double tz=Z[t][k]; Z[t][k]=Z[t][jm]; Z[t][jm]=tz;
    }
  }
  if (t<4) out[t] = (float)dv;
  for (int k=0;k<4;++k) scal[192 + t*4 + k] = (float)Z[t][k];
}

extern "C" void kernel_launch(void* const* d_in, const int* in_sizes, int n_in,
                              void* d_out, int out_size, void* d_ws, size_t ws_size,
                              hipStream_t stream){
  (void)in_sizes; (void)n_in; (void)out_size;
  const float* B0   = (const float*)d_in[0];
  const float* Bext = (const float*)d_in[1];
  const float* phi  = (const float*)d_in[2];
  float* out = (float*)d_out;

  size_t need_big = ((size_t)(MKRY+2)*DIM)*4 + 1024*8 + 512*4 + 256;
  int vmod; bool big;
  if (ws_size >= need_big + (1u<<20)) { vmod = MKRY+1; big = true; }
  else                               { vmod = 3;      big = false; }

  float* vbase = (float*)d_ws;
  float* wring = vbase + (size_t)vmod*DIM;   // spacing kept; wring unused now
  double* part = (double*)(wring + 2*(size_t)DIM);
  float* scal  = (float*)(part + 1024);
  unsigned* bar = (unsigned*)(scal + 512);

  hipLaunchKernelGGL(k_init, dim3(1), dim3(1), 0, stream, bar);
  {
    void* args[] = { (void*)&B0, (void*)&Bext, (void*)&phi,
                     (void*)&vbase, (void*)&vmod,
                     (void*)&part, (void*)&scal, (void*)&bar };
    (void)hipLaunchCooperativeKernel((const void*)k_pass1, dim3(NBLOCK), dim3(TPB), args, 0, stream);
  }
  hipLaunchKernelGGL(k_eigh, dim3(1), dim3(64), 0, stream, scal, out);
  if (big){
    hipLaunchKernelGGL(k_pass2s, dim3(DIM/256), dim3(256), 0, stream, vbase, scal, out);
  } else {
    int baseEpoch = 2 + 2*MKRY;   // epochs consumed by pass1
    void* args[] = { (void*)&vbase, (void*)&vmod, (void*)&scal,
                     (void*)&out, (void*)&bar, (void*)&baseEpoch };
    (void)hipLaunchCooperativeKernel((const void*)k_pass2c, dim3(NBLOCK), dim3(TPB), args, 0, stream);
  }
}